// Round 15
// baseline (185.677 us; speedup 1.0000x reference)
//
#include <hip/hip_runtime.h>

typedef _Float16 f16;
typedef _Float16 f16x8 __attribute__((ext_vector_type(8)));
typedef float f32x4 __attribute__((ext_vector_type(4)));
typedef float f32x16 __attribute__((ext_vector_type(16)));
typedef uint32_t u32x4 __attribute__((ext_vector_type(4)));

#define NBLK 8
#define NIMG 14
#define MFMA32(a, b, c) __builtin_amdgcn_mfma_f32_32x32x16_f16(a, b, c, 0, 0, 0)
#define LOG2E 1.4426950408889634f

// Consumer A-image K-slot -> producer feature index (32x32x16 chaining).
// Producer D: col=lane&31, row=(reg&3)+8*(reg>>2)+4*(lane>>5)  [m74/m101].
// Consumer fragment j = producer regs [8*(j&1), +8) of tile (j>>1)  ->
// feature at consumer k-slot (k=8*hi+e):
__device__ __forceinline__ int pinv32(int j, int k) {
  return 32 * (j >> 1) + (k & 3) + 8 * (2 * (j & 1) + ((k >> 2) & 1)) + 4 * (k >> 3);
}
__device__ __forceinline__ float hi_part(float v) { return (float)(f16)v; }  // RNE
__device__ __forceinline__ float lo_part(float v) { f16 h = (f16)v; return v - (float)h; }

__device__ __forceinline__ float fast_exp2(float x) {
  float r; asm("v_exp_f32 %0, %1" : "=v"(r) : "v"(x)); return r;
}
__device__ __forceinline__ float fast_rcp(float x) {
  float r; asm("v_rcp_f32 %0, %1" : "=v"(r) : "v"(x)); return r;
}
__device__ __forceinline__ uint32_t pkrtz_u(float a, float b) {
  auto p = __builtin_amdgcn_cvt_pkrtz(a, b);
  return __builtin_bit_cast(uint32_t, p);
}
// Packed lo-residual for the x-state split (used in B1 only).
__device__ __forceinline__ uint32_t mix_lo_pk(uint32_t hi_pk, float neg1,
                                              float r0, float r1) {
  uint32_t d;
  asm("v_fma_mixlo_f16 %0, %1, %2, %3 op_sel:[0,0,0] op_sel_hi:[1,0,0]\n\t"
      "v_fma_mixhi_f16 %0, %1, %2, %4 op_sel:[1,0,0] op_sel_hi:[1,0,0]"
      : "=&v"(d)
      : "v"(hi_pk), "v"(neg1), "v"(r0), "v"(r1));
  return d;
}

// One-time prep for 32x32x16 fragments. Per block i (img 0..13, 512 f16):
//   img 0,1   A1[T]: rows m=32T+(l&31); K slots (k=8*(l>>5)+e):
//     k0-3 W1hi (pairs x-hi), k4-7 W1lo (pairs x-hi), k8-11 W1hi (pairs x-lo),
//     k12/k13 b1 hi/lo (pair 1), k14,15 zero.
//   img 2..9  A2[T2*4+j]: W2 RNE f16, column pinv32(j,k)
//   img 10..13 A3[j]: W3 RNE f16, rows replicated (row <- row&3), pre-scaled
//     (rows 0,1 x 0.2*log2e; rows 2,3 x 0.1), column pinv32(j,k)
// img 14: couple constants cwp[i*24+..] ([0..15] Wp*diag(sc), [16..19] Wp*go,
//   [20..23] b3 scaled; cwp[192]=sum log scale) and cwp2[i*64+..] = b2
//   reordered to the 32x32 C/D register layout (T2, hi, reg).
__global__ void prep_weights(const float* __restrict__ W1, const float* __restrict__ b1,
                             const float* __restrict__ W2, const float* __restrict__ W3,
                             const float* __restrict__ b2, const float* __restrict__ b3,
                             const float* __restrict__ w_perm,
                             const float* __restrict__ g_scale, const float* __restrict__ g_offset,
                             f16* __restrict__ wsp, float* __restrict__ cwp,
                             float* __restrict__ cwp2) {
  int i = blockIdx.x / (NIMG + 1);
  int img = blockIdx.x % (NIMG + 1);
  if (img == NIMG) {
    int tid = threadIdx.x;
    if (tid < 16) {
      int cc = tid & 3;
      float gs = g_scale[i * 4 + cc];
      float sc = 0.2f * log1pf(expf(0.5f * gs));
      cwp[i * 24 + tid] = w_perm[i * 16 + tid] * sc;
    } else if (tid < 20) {
      int r = tid - 16;
      float acc = 0.f;
      for (int cc = 0; cc < 4; ++cc)
        acc += w_perm[i * 16 + r * 4 + cc] * g_offset[i * 4 + cc];
      cwp[i * 24 + 16 + r] = acc;
    } else if (tid < 24) {
      int j = tid - 20;
      float scale = (j < 2) ? (0.2f * LOG2E) : 0.1f;
      cwp[i * 24 + 20 + j] = b3[i * 4 + j] * scale;
    } else if (tid == 24 && i == 0) {
      float acc = 0.f;
      for (int k = 0; k < 32; ++k)
        acc += logf(0.2f * log1pf(expf(0.5f * g_scale[k])));
      cwp[192] = acc;
    }
    // b2 reordered to C/D reg layout: tid -> (T2=tid>>5, hi=(tid>>4)&1, r=tid&15)
    {
      int T2 = threadIdx.x >> 5, hi = (threadIdx.x >> 4) & 1, r = threadIdx.x & 15;
      cwp2[i * 64 + threadIdx.x] =
          b2[i * 64 + 32 * T2 + (r & 3) + 8 * (r >> 2) + 4 * hi];
    }
    return;
  }
  int lane = threadIdx.x;
  int row = lane & 31, hi = lane >> 5;
  f16 vals[8];
#pragma unroll
  for (int e = 0; e < 8; ++e) {
    int k = 8 * hi + e;
    float out = 0.f;
    if (img < 2) {
      int m = 32 * img + row;
      if (k < 4)        out = hi_part(W1[i * 256 + m * 4 + k]);
      else if (k < 8)   out = lo_part(W1[i * 256 + m * 4 + (k - 4)]);
      else if (k < 12)  out = hi_part(W1[i * 256 + m * 4 + (k - 8)]);
      else if (k == 12) out = hi_part(b1[i * 64 + m]);
      else if (k == 13) out = lo_part(b1[i * 64 + m]);
      else out = 0.f;
    } else if (img < 10) {
      int q = img - 2, T2 = q >> 2, j = q & 3;
      int m = 32 * T2 + row;
      out = hi_part(W2[i * 4096 + m * 64 + pinv32(j, k)]);
    } else {
      int j = img - 10;
      int rr = row & 3;  // replicate W3 rows -> d3 regs 0..3 = a0..a3 everywhere
      float rs = (rr < 2) ? (0.2f * LOG2E) : 0.1f;
      out = hi_part(W3[i * 256 + rr * 64 + pinv32(j, k)] * rs);
    }
    vals[e] = (f16)out;
  }
  f16x8 vv = {vals[0], vals[1], vals[2], vals[3], vals[4], vals[5], vals[6], vals[7]};
  *(f16x8*)(wsp + ((size_t)i * NIMG + img) * 512 + (size_t)lane * 8) = vv;
}

// 8 consecutive D regs -> packed RTZ f16 + packed relu (8 VALU ops).
template <int OFF>
__device__ __forceinline__ f16x8 cvt_relu(const f32x16 d, uint32_t zero_u) {
  u32x4 u;
  u[0] = pkrtz_u(d[OFF + 0], d[OFF + 1]);
  u[1] = pkrtz_u(d[OFF + 2], d[OFF + 3]);
  u[2] = pkrtz_u(d[OFF + 4], d[OFF + 5]);
  u[3] = pkrtz_u(d[OFF + 6], d[OFF + 7]);
#pragma unroll
  for (int p = 0; p < 4; ++p) {
    uint32_t r;
    asm("v_pk_max_f16 %0, %1, %2" : "=v"(r) : "v"(u[p]), "v"(zero_u));
    u[p] = r;
  }
  return __builtin_bit_cast(f16x8, u);
}

// One wave = 32 points (one per column-lane pair). 14 MFMAs of 32x32x16 per
// block-iter (L1 2, L2 2x4-chain, L3 4-chain) — half the MFMA instructions
// per point of the 16x16x32 form. Fragment chaining is register-contiguous.
__global__ __launch_bounds__(256) void cinn_mfma_kernel(
    const float* __restrict__ q_feat, const float* __restrict__ Hc,
    const f16* __restrict__ wf, const float* __restrict__ cwp,
    const float* __restrict__ cwp2,
    float* __restrict__ out_x, float* __restrict__ out_ld, int n) {
  int lane = threadIdx.x & 63;
  int col = lane & 31;
  bool h0 = (lane < 32);
  int wave = (blockIdx.x * blockDim.x + threadIdx.x) >> 6;
  float neg1 = -1.0f;
  uint32_t zero_u = 0u;
  const uint32_t ones_pk = 0x3C003C00u;

  int p = wave * 32 + col;
  if (p >= n) p = n - 1;  // clamped lanes compute identical results (benign)
  float4 xv = *reinterpret_cast<const float4*>(q_feat + (size_t)p * 4);
  float x0 = xv.x, x1 = xv.y, x2 = xv.z, x3 = xv.w;
  float ld = 0.f;
  float2 hv = *reinterpret_cast<const float2*>(Hc + (size_t)p * 2);
  uint32_t ch_pk = pkrtz_u(hv.x, hv.y);
  uint32_t cl_pk = mix_lo_pk(ch_pk, neg1, hv.x, hv.y);

  const f32x16 zero16 = {0.f, 0.f, 0.f, 0.f, 0.f, 0.f, 0.f, 0.f,
                         0.f, 0.f, 0.f, 0.f, 0.f, 0.f, 0.f, 0.f};

#pragma unroll 1
  for (int i = 0; i < NBLK; ++i) {
    const f16* wb = wf + (size_t)i * NIMG * 512 + (size_t)lane * 8;
    const float* cw = cwp + i * 24;

    // B1 (k=8*hi+e): hi=0 -> {xh,ch,xh,ch} (pairs W1hi, W1lo);
    //                hi=1 -> {xl,cl,ones,0} (pairs W1hi, bias)
    uint32_t xh_pk = pkrtz_u(x0, x1);
    uint32_t xl_pk = mix_lo_pk(xh_pk, neg1, x0, x1);
    u32x4 B1u = {h0 ? xh_pk : xl_pk,
                 h0 ? ch_pk : cl_pk,
                 h0 ? xh_pk : ones_pk,
                 h0 ? ch_pk : 0u};
    f16x8 B1 = __builtin_bit_cast(f16x8, B1u);

    // L1: two output tiles (features 0-31, 32-63)
    f32x16 d1a = MFMA32(*(const f16x8*)(wb + 0 * 512), B1, zero16);
    f32x16 d1b = MFMA32(*(const f16x8*)(wb + 1 * 512), B1, zero16);
    f16x8 bf[4];
    bf[0] = cvt_relu<0>(d1a, zero_u);
    bf[1] = cvt_relu<8>(d1a, zero_u);
    bf[2] = cvt_relu<0>(d1b, zero_u);
    bf[3] = cvt_relu<8>(d1b, zero_u);

    // L2: per output tile, K=64 via 4 chained MFMAs; b2 enters as C-input
    f16x8 b3f[4];
#pragma unroll
    for (int T2 = 0; T2 < 2; ++T2) {
      const f32x16 cin = *(const f32x16*)(cwp2 + i * 64 + T2 * 32 + (h0 ? 0 : 16));
      f32x16 acc = MFMA32(*(const f16x8*)(wb + (2 + T2 * 4 + 0) * 512), bf[0], cin);
      acc = MFMA32(*(const f16x8*)(wb + (2 + T2 * 4 + 1) * 512), bf[1], acc);
      acc = MFMA32(*(const f16x8*)(wb + (2 + T2 * 4 + 2) * 512), bf[2], acc);
      acc = MFMA32(*(const f16x8*)(wb + (2 + T2 * 4 + 3) * 512), bf[3], acc);
      b3f[2 * T2 + 0] = cvt_relu<0>(acc, zero_u);
      b3f[2 * T2 + 1] = cvt_relu<8>(acc, zero_u);
    }

    // L3: rows replicated -> regs 0..3 = {2a0*log2e, 2a1*log2e, t2, t3}
    f32x16 d3 = MFMA32(*(const f16x8*)(wb + 10 * 512), b3f[0], zero16);
    d3 = MFMA32(*(const f16x8*)(wb + 11 * 512), b3f[1], d3);
    d3 = MFMA32(*(const f16x8*)(wb + 12 * 512), b3f[2], d3);
    d3 = MFMA32(*(const f16x8*)(wb + 13 * 512), b3f[3], d3);

    // couple (shuffle-free)
    float a0 = d3[0] + cw[20];
    float a1 = d3[1] + cw[21];
    float t2 = d3[2] + cw[22];
    float t3 = d3[3] + cw[23];
    float u0 = fast_exp2(a0), u1 = fast_exp2(a1);      // e^{2a}
    float s0 = fmaf(-4.f, fast_rcp(u0 + 1.f), 2.f);    // 2*tanh(a)
    float s1 = fmaf(-4.f, fast_rcp(u1 + 1.f), 2.f);
    float e0 = fast_exp2(s0 * LOG2E), e1 = fast_exp2(s1 * LOG2E);
    x2 = fmaf(x2, e0, t2);
    x3 = fmaf(x3, e1, t3);
    ld += s0 + s1;
    // fused actnorm+permutation
    float nx0 = fmaf(x0, cw[0],  fmaf(x1, cw[1],  fmaf(x2, cw[2],  fmaf(x3, cw[3],  cw[16]))));
    float nx1 = fmaf(x0, cw[4],  fmaf(x1, cw[5],  fmaf(x2, cw[6],  fmaf(x3, cw[7],  cw[17]))));
    float nx2 = fmaf(x0, cw[8],  fmaf(x1, cw[9],  fmaf(x2, cw[10], fmaf(x3, cw[11], cw[18]))));
    float nx3 = fmaf(x0, cw[12], fmaf(x1, cw[13], fmaf(x2, cw[14], fmaf(x3, cw[15], cw[19]))));
    x0 = nx0; x1 = nx1; x2 = nx2; x3 = nx3;
  }

  if (lane < 32) {
    *reinterpret_cast<float4*>(out_x + (size_t)p * 4) = make_float4(x0, x1, x2, x3);
    out_ld[p] = ld + cwp[192];
  }
}

extern "C" void kernel_launch(void* const* d_in, const int* in_sizes, int n_in,
                              void* d_out, int out_size, void* d_ws, size_t ws_size,
                              hipStream_t stream) {
  const float* q_feat   = (const float*)d_in[0];
  const float* Hc       = (const float*)d_in[1];
  const float* W1       = (const float*)d_in[2];
  const float* b1       = (const float*)d_in[3];
  const float* W2       = (const float*)d_in[4];
  const float* b2       = (const float*)d_in[5];
  const float* W3       = (const float*)d_in[6];
  const float* b3       = (const float*)d_in[7];
  const float* w_perm   = (const float*)d_in[8];
  const float* g_scale  = (const float*)d_in[9];
  const float* g_offset = (const float*)d_in[10];

  int n = in_sizes[0] / 4;
  float* out_x  = (float*)d_out;
  float* out_ld = out_x + (size_t)n * 4;
  f16* wf = (f16*)d_ws;                           // 8*14*512*2 = 114688 B
  float* cwp  = (float*)((char*)d_ws + 114688);   // 193 floats
  float* cwp2 = (float*)((char*)d_ws + 115712);   // 512 floats (b2 reordered)

  hipLaunchKernelGGL(prep_weights, dim3(NBLK * (NIMG + 1)), dim3(64), 0, stream,
                     W1, b1, W2, W3, b2, b3, w_perm, g_scale, g_offset,
                     wf, cwp, cwp2);
  int blocks = (n + 127) / 128;  // 128 points per 256-thread block (32/wave)
  hipLaunchKernelGGL(cinn_mfma_kernel, dim3(blocks), dim3(256), 0, stream,
                     q_feat, Hc, wf, cwp, cwp2, out_x, out_ld, n);
}

// Round 16
// 155.855 us; speedup vs baseline: 1.1914x; 1.1914x over previous
//
#include <hip/hip_runtime.h>

typedef _Float16 f16;
typedef _Float16 f16x8 __attribute__((ext_vector_type(8)));
typedef float f32x4 __attribute__((ext_vector_type(4)));
typedef float f32x16 __attribute__((ext_vector_type(16)));
typedef uint32_t u32x4 __attribute__((ext_vector_type(4)));

#define NBLK 8
#define NS 2   // independent 32-point streams per wave
#define NIMG 14
#define MFMA32(a, b, c) __builtin_amdgcn_mfma_f32_32x32x16_f16(a, b, c, 0, 0, 0)
#define LOG2E 1.4426950408889634f

// Consumer A-image K-slot -> producer feature index (32x32x16 chaining).
// Producer D: col=lane&31, row=(reg&3)+8*(reg>>2)+4*(lane>>5)  [m74/m101].
// Consumer fragment j = producer regs [8*(j&1), +8) of tile (j>>1).
__device__ __forceinline__ int pinv32(int j, int k) {
  return 32 * (j >> 1) + (k & 3) + 8 * (2 * (j & 1) + ((k >> 2) & 1)) + 4 * (k >> 3);
}
__device__ __forceinline__ float hi_part(float v) { return (float)(f16)v; }  // RNE
__device__ __forceinline__ float lo_part(float v) { f16 h = (f16)v; return v - (float)h; }

__device__ __forceinline__ float fast_exp2(float x) {
  float r; asm("v_exp_f32 %0, %1" : "=v"(r) : "v"(x)); return r;
}
__device__ __forceinline__ float fast_rcp(float x) {
  float r; asm("v_rcp_f32 %0, %1" : "=v"(r) : "v"(x)); return r;
}
__device__ __forceinline__ uint32_t pkrtz_u(float a, float b) {
  auto p = __builtin_amdgcn_cvt_pkrtz(a, b);
  return __builtin_bit_cast(uint32_t, p);
}
// Packed lo-residual for the x-state split (used in B1 only).
__device__ __forceinline__ uint32_t mix_lo_pk(uint32_t hi_pk, float neg1,
                                              float r0, float r1) {
  uint32_t d;
  asm("v_fma_mixlo_f16 %0, %1, %2, %3 op_sel:[0,0,0] op_sel_hi:[1,0,0]\n\t"
      "v_fma_mixhi_f16 %0, %1, %2, %4 op_sel:[1,0,0] op_sel_hi:[1,0,0]"
      : "=&v"(d)
      : "v"(hi_pk), "v"(neg1), "v"(r0), "v"(r1));
  return d;
}

// One-time prep for 32x32x16 fragments (identical to R15 — verified).
// Per block i (img 0..13, 512 f16):
//   img 0,1   A1[T]: rows m=32T+(l&31); K slots (k=8*(l>>5)+e):
//     k0-3 W1hi (pairs x-hi), k4-7 W1lo (pairs x-hi), k8-11 W1hi (pairs x-lo),
//     k12/k13 b1 hi/lo, k14,15 zero.
//   img 2..9  A2[T2*4+j]: W2 RNE f16, column pinv32(j,k)
//   img 10..13 A3[j]: W3 RNE f16, rows replicated (row <- row&3), pre-scaled
//     (rows 0,1 x 0.2*log2e; rows 2,3 x 0.1), column pinv32(j,k)
// img 14: couple constants cwp + b2 reordered to C/D reg layout (cwp2).
__global__ void prep_weights(const float* __restrict__ W1, const float* __restrict__ b1,
                             const float* __restrict__ W2, const float* __restrict__ W3,
                             const float* __restrict__ b2, const float* __restrict__ b3,
                             const float* __restrict__ w_perm,
                             const float* __restrict__ g_scale, const float* __restrict__ g_offset,
                             f16* __restrict__ wsp, float* __restrict__ cwp,
                             float* __restrict__ cwp2) {
  int i = blockIdx.x / (NIMG + 1);
  int img = blockIdx.x % (NIMG + 1);
  if (img == NIMG) {
    int tid = threadIdx.x;
    if (tid < 16) {
      int cc = tid & 3;
      float gs = g_scale[i * 4 + cc];
      float sc = 0.2f * log1pf(expf(0.5f * gs));
      cwp[i * 24 + tid] = w_perm[i * 16 + tid] * sc;
    } else if (tid < 20) {
      int r = tid - 16;
      float acc = 0.f;
      for (int cc = 0; cc < 4; ++cc)
        acc += w_perm[i * 16 + r * 4 + cc] * g_offset[i * 4 + cc];
      cwp[i * 24 + 16 + r] = acc;
    } else if (tid < 24) {
      int j = tid - 20;
      float scale = (j < 2) ? (0.2f * LOG2E) : 0.1f;
      cwp[i * 24 + 20 + j] = b3[i * 4 + j] * scale;
    } else if (tid == 24 && i == 0) {
      float acc = 0.f;
      for (int k = 0; k < 32; ++k)
        acc += logf(0.2f * log1pf(expf(0.5f * g_scale[k])));
      cwp[192] = acc;
    }
    {
      int T2 = threadIdx.x >> 5, hi = (threadIdx.x >> 4) & 1, r = threadIdx.x & 15;
      cwp2[i * 64 + threadIdx.x] =
          b2[i * 64 + 32 * T2 + (r & 3) + 8 * (r >> 2) + 4 * hi];
    }
    return;
  }
  int lane = threadIdx.x;
  int row = lane & 31, hi = lane >> 5;
  f16 vals[8];
#pragma unroll
  for (int e = 0; e < 8; ++e) {
    int k = 8 * hi + e;
    float out = 0.f;
    if (img < 2) {
      int m = 32 * img + row;
      if (k < 4)        out = hi_part(W1[i * 256 + m * 4 + k]);
      else if (k < 8)   out = lo_part(W1[i * 256 + m * 4 + (k - 4)]);
      else if (k < 12)  out = hi_part(W1[i * 256 + m * 4 + (k - 8)]);
      else if (k == 12) out = hi_part(b1[i * 64 + m]);
      else if (k == 13) out = lo_part(b1[i * 64 + m]);
      else out = 0.f;
    } else if (img < 10) {
      int q = img - 2, T2 = q >> 2, j = q & 3;
      int m = 32 * T2 + row;
      out = hi_part(W2[i * 4096 + m * 64 + pinv32(j, k)]);
    } else {
      int j = img - 10;
      int rr = row & 3;  // replicate W3 rows -> d3 regs 0..3 = a0..a3 everywhere
      float rs = (rr < 2) ? (0.2f * LOG2E) : 0.1f;
      out = hi_part(W3[i * 256 + rr * 64 + pinv32(j, k)] * rs);
    }
    vals[e] = (f16)out;
  }
  f16x8 vv = {vals[0], vals[1], vals[2], vals[3], vals[4], vals[5], vals[6], vals[7]};
  *(f16x8*)(wsp + ((size_t)i * NIMG + img) * 512 + (size_t)lane * 8) = vv;
}

// 8 consecutive D regs -> packed RTZ f16 + packed relu (8 VALU ops).
template <int OFF>
__device__ __forceinline__ f16x8 cvt_relu(const f32x16 d, uint32_t zero_u) {
  u32x4 u;
  u[0] = pkrtz_u(d[OFF + 0], d[OFF + 1]);
  u[1] = pkrtz_u(d[OFF + 2], d[OFF + 3]);
  u[2] = pkrtz_u(d[OFF + 4], d[OFF + 5]);
  u[3] = pkrtz_u(d[OFF + 6], d[OFF + 7]);
#pragma unroll
  for (int p = 0; p < 4; ++p) {
    uint32_t r;
    asm("v_pk_max_f16 %0, %1, %2" : "=v"(r) : "v"(u[p]), "v"(zero_u));
    u[p] = r;
  }
  return __builtin_bit_cast(f16x8, u);
}

struct Pt {
  float x0, x1, x2, x3, ld;
  uint32_t ch_pk, cl_pk;
};

// Dual-stream 32x32: each wave handles 64 points (2 streams x 32). All
// A-fragments and the b2 C-input are shared between streams; each stream's
// 4-deep dependent MFMA chains interleave with the other's (the R5 ILP fix,
// applied to the 2x-more-MFMA-efficient 32x32 shape).
__global__ __launch_bounds__(256) void cinn_mfma_kernel(
    const float* __restrict__ q_feat, const float* __restrict__ Hc,
    const f16* __restrict__ wf, const float* __restrict__ cwp,
    const float* __restrict__ cwp2,
    float* __restrict__ out_x, float* __restrict__ out_ld, int n) {
  int lane = threadIdx.x & 63;
  int col = lane & 31;
  bool h0 = (lane < 32);
  int wave = (blockIdx.x * blockDim.x + threadIdx.x) >> 6;
  float neg1 = -1.0f;
  uint32_t zero_u = 0u;
  const uint32_t ones_pk = 0x3C003C00u;

  int pt[NS];
  Pt st[NS];
#pragma unroll
  for (int u = 0; u < NS; ++u) {
    int p = wave * (32 * NS) + u * 32 + col;
    if (p >= n) p = n - 1;  // clamped lanes compute identical results (benign)
    pt[u] = p;
    float4 xv = *reinterpret_cast<const float4*>(q_feat + (size_t)p * 4);
    st[u].x0 = xv.x; st[u].x1 = xv.y; st[u].x2 = xv.z; st[u].x3 = xv.w;
    st[u].ld = 0.f;
    float2 hv = *reinterpret_cast<const float2*>(Hc + (size_t)p * 2);
    st[u].ch_pk = pkrtz_u(hv.x, hv.y);
    st[u].cl_pk = mix_lo_pk(st[u].ch_pk, neg1, hv.x, hv.y);
  }

  const f32x16 zero16 = {0.f, 0.f, 0.f, 0.f, 0.f, 0.f, 0.f, 0.f,
                         0.f, 0.f, 0.f, 0.f, 0.f, 0.f, 0.f, 0.f};

#pragma unroll 1
  for (int i = 0; i < NBLK; ++i) {
    const f16* wb = wf + (size_t)i * NIMG * 512 + (size_t)lane * 8;
    const float* cw = cwp + i * 24;

    // B1 (k=8*hi+e): hi=0 -> {xh,ch,xh,ch}; hi=1 -> {xl,cl,ones,0}
    f16x8 B1[NS];
#pragma unroll
    for (int u = 0; u < NS; ++u) {
      uint32_t xh_pk = pkrtz_u(st[u].x0, st[u].x1);
      uint32_t xl_pk = mix_lo_pk(xh_pk, neg1, st[u].x0, st[u].x1);
      u32x4 B1u = {h0 ? xh_pk : xl_pk,
                   h0 ? st[u].ch_pk : st[u].cl_pk,
                   h0 ? xh_pk : ones_pk,
                   h0 ? st[u].ch_pk : 0u};
      B1[u] = __builtin_bit_cast(f16x8, B1u);
    }

    // L1: two output tiles (features 0-31, 32-63); A-frags shared
    f16x8 bf[NS][4];
    {
      f16x8 a0 = *(const f16x8*)(wb + 0 * 512);
      f16x8 a1 = *(const f16x8*)(wb + 1 * 512);
#pragma unroll
      for (int u = 0; u < NS; ++u) {
        f32x16 d1a = MFMA32(a0, B1[u], zero16);
        f32x16 d1b = MFMA32(a1, B1[u], zero16);
        bf[u][0] = cvt_relu<0>(d1a, zero_u);
        bf[u][1] = cvt_relu<8>(d1a, zero_u);
        bf[u][2] = cvt_relu<0>(d1b, zero_u);
        bf[u][3] = cvt_relu<8>(d1b, zero_u);
      }
    }

    // L2: per output tile, K=64 via 4 chained MFMAs; streams interleaved so
    // dependent MFMAs are 2 apart; b2 (cwp2) enters as shared C-input.
    f16x8 b3f[NS][4];
#pragma unroll
    for (int T2 = 0; T2 < 2; ++T2) {
      f16x8 ap0 = *(const f16x8*)(wb + (2 + T2 * 4 + 0) * 512);
      f16x8 ap1 = *(const f16x8*)(wb + (2 + T2 * 4 + 1) * 512);
      f16x8 ap2 = *(const f16x8*)(wb + (2 + T2 * 4 + 2) * 512);
      f16x8 ap3 = *(const f16x8*)(wb + (2 + T2 * 4 + 3) * 512);
      const f32x16 cin = *(const f32x16*)(cwp2 + i * 64 + T2 * 32 + (h0 ? 0 : 16));
      f32x16 acc[NS];
#pragma unroll
      for (int u = 0; u < NS; ++u) acc[u] = MFMA32(ap0, bf[u][0], cin);
#pragma unroll
      for (int u = 0; u < NS; ++u) acc[u] = MFMA32(ap1, bf[u][1], acc[u]);
#pragma unroll
      for (int u = 0; u < NS; ++u) acc[u] = MFMA32(ap2, bf[u][2], acc[u]);
#pragma unroll
      for (int u = 0; u < NS; ++u) acc[u] = MFMA32(ap3, bf[u][3], acc[u]);
#pragma unroll
      for (int u = 0; u < NS; ++u) {
        b3f[u][2 * T2 + 0] = cvt_relu<0>(acc[u], zero_u);
        b3f[u][2 * T2 + 1] = cvt_relu<8>(acc[u], zero_u);
      }
    }

    // L3: rows replicated -> regs 0..3 = {2a0*log2e, 2a1*log2e, t2, t3}
    f32x16 d3[NS];
    {
      f16x8 a0 = *(const f16x8*)(wb + 10 * 512);
      f16x8 a1 = *(const f16x8*)(wb + 11 * 512);
      f16x8 a2 = *(const f16x8*)(wb + 12 * 512);
      f16x8 a3 = *(const f16x8*)(wb + 13 * 512);
#pragma unroll
      for (int u = 0; u < NS; ++u) d3[u] = MFMA32(a0, b3f[u][0], zero16);
#pragma unroll
      for (int u = 0; u < NS; ++u) d3[u] = MFMA32(a1, b3f[u][1], d3[u]);
#pragma unroll
      for (int u = 0; u < NS; ++u) d3[u] = MFMA32(a2, b3f[u][2], d3[u]);
#pragma unroll
      for (int u = 0; u < NS; ++u) d3[u] = MFMA32(a3, b3f[u][3], d3[u]);
    }

    // couple (shuffle-free) per stream
#pragma unroll
    for (int u = 0; u < NS; ++u) {
      float a0 = d3[u][0] + cw[20];
      float a1 = d3[u][1] + cw[21];
      float t2 = d3[u][2] + cw[22];
      float t3 = d3[u][3] + cw[23];
      float u0 = fast_exp2(a0), u1 = fast_exp2(a1);      // e^{2a}
      float s0 = fmaf(-4.f, fast_rcp(u0 + 1.f), 2.f);    // 2*tanh(a)
      float s1 = fmaf(-4.f, fast_rcp(u1 + 1.f), 2.f);
      float e0 = fast_exp2(s0 * LOG2E), e1 = fast_exp2(s1 * LOG2E);
      st[u].x2 = fmaf(st[u].x2, e0, t2);
      st[u].x3 = fmaf(st[u].x3, e1, t3);
      st[u].ld += s0 + s1;
      float nx0 = fmaf(st[u].x0, cw[0],  fmaf(st[u].x1, cw[1],  fmaf(st[u].x2, cw[2],  fmaf(st[u].x3, cw[3],  cw[16]))));
      float nx1 = fmaf(st[u].x0, cw[4],  fmaf(st[u].x1, cw[5],  fmaf(st[u].x2, cw[6],  fmaf(st[u].x3, cw[7],  cw[17]))));
      float nx2 = fmaf(st[u].x0, cw[8],  fmaf(st[u].x1, cw[9],  fmaf(st[u].x2, cw[10], fmaf(st[u].x3, cw[11], cw[18]))));
      float nx3 = fmaf(st[u].x0, cw[12], fmaf(st[u].x1, cw[13], fmaf(st[u].x2, cw[14], fmaf(st[u].x3, cw[15], cw[19]))));
      st[u].x0 = nx0; st[u].x1 = nx1; st[u].x2 = nx2; st[u].x3 = nx3;
    }
  }

  if (lane < 32) {
    float lt = cwp[192];
#pragma unroll
    for (int u = 0; u < NS; ++u) {
      *reinterpret_cast<float4*>(out_x + (size_t)pt[u] * 4) =
          make_float4(st[u].x0, st[u].x1, st[u].x2, st[u].x3);
      out_ld[pt[u]] = st[u].ld + lt;
    }
  }
}

extern "C" void kernel_launch(void* const* d_in, const int* in_sizes, int n_in,
                              void* d_out, int out_size, void* d_ws, size_t ws_size,
                              hipStream_t stream) {
  const float* q_feat   = (const float*)d_in[0];
  const float* Hc       = (const float*)d_in[1];
  const float* W1       = (const float*)d_in[2];
  const float* b1       = (const float*)d_in[3];
  const float* W2       = (const float*)d_in[4];
  const float* b2       = (const float*)d_in[5];
  const float* W3       = (const float*)d_in[6];
  const float* b3       = (const float*)d_in[7];
  const float* w_perm   = (const float*)d_in[8];
  const float* g_scale  = (const float*)d_in[9];
  const float* g_offset = (const float*)d_in[10];

  int n = in_sizes[0] / 4;
  float* out_x  = (float*)d_out;
  float* out_ld = out_x + (size_t)n * 4;
  f16* wf = (f16*)d_ws;                           // 8*14*512*2 = 114688 B
  float* cwp  = (float*)((char*)d_ws + 114688);   // 193 floats
  float* cwp2 = (float*)((char*)d_ws + 115712);   // 512 floats (b2 reordered)

  hipLaunchKernelGGL(prep_weights, dim3(NBLK * (NIMG + 1)), dim3(64), 0, stream,
                     W1, b1, W2, W3, b2, b3, w_perm, g_scale, g_offset,
                     wf, cwp, cwp2);
  int blocks = (n + 255) / 256;  // 256 points per 256-thread block (64/wave)
  hipLaunchKernelGGL(cinn_mfma_kernel, dim3(blocks), dim3(256), 0, stream,
                     q_feat, Hc, wf, cwp, cwp2, out_x, out_ld, n);
}

// Round 17
// 153.756 us; speedup vs baseline: 1.2076x; 1.0136x over previous
//
#include <hip/hip_runtime.h>

typedef _Float16 f16;
typedef _Float16 f16x8 __attribute__((ext_vector_type(8)));
typedef float f32x4 __attribute__((ext_vector_type(4)));
typedef float f32x16 __attribute__((ext_vector_type(16)));
typedef uint32_t u32x4 __attribute__((ext_vector_type(4)));

#define NBLK 8
#define NS 2   // independent 32-point streams per wave
#define NIMG 14
#define MFMA32(a, b, c) __builtin_amdgcn_mfma_f32_32x32x16_f16(a, b, c, 0, 0, 0)
#define LOG2E 1.4426950408889634f

// Consumer A-image K-slot -> producer feature index (32x32x16 chaining).
// Producer D: col=lane&31, row=(reg&3)+8*(reg>>2)+4*(lane>>5)  [m74/m101].
// Consumer fragment j = producer regs [8*(j&1), +8) of tile (j>>1).
__device__ __forceinline__ int pinv32(int j, int k) {
  return 32 * (j >> 1) + (k & 3) + 8 * (2 * (j & 1) + ((k >> 2) & 1)) + 4 * (k >> 3);
}
__device__ __forceinline__ float hi_part(float v) { return (float)(f16)v; }  // RNE

__device__ __forceinline__ float fast_exp2(float x) {
  float r; asm("v_exp_f32 %0, %1" : "=v"(r) : "v"(x)); return r;
}
__device__ __forceinline__ float fast_rcp(float x) {
  float r; asm("v_rcp_f32 %0, %1" : "=v"(r) : "v"(x)); return r;
}
__device__ __forceinline__ uint32_t pkrtz_u(float a, float b) {
  auto p = __builtin_amdgcn_cvt_pkrtz(a, b);
  return __builtin_bit_cast(uint32_t, p);
}

// One-time prep for 32x32x16 fragments. Per block i (img 0..13, 512 f16):
//   img 0,1   A1[T]: rows m=32T+(l&31); K slots (k=8*(l>>5)+e):
//     k0-3 = W1 (RNE f16), k4 = b1, k5..15 = 0.  (All lo-corrections dropped:
//     every prior f16 quantization left absmax at the f32 floor 0.03125.)
//   img 2..9  A2[T2*4+j]: W2 RNE f16, column pinv32(j,k)
//   img 10..13 A3[j]: W3 RNE f16, rows replicated (row <- row&3), pre-scaled
//     (rows 0,1 x 0.2*log2e; rows 2,3 x 0.1), column pinv32(j,k)
// img 14: couple constants cwp + b2 reordered to C/D reg layout (cwp2).
__global__ void prep_weights(const float* __restrict__ W1, const float* __restrict__ b1,
                             const float* __restrict__ W2, const float* __restrict__ W3,
                             const float* __restrict__ b2, const float* __restrict__ b3,
                             const float* __restrict__ w_perm,
                             const float* __restrict__ g_scale, const float* __restrict__ g_offset,
                             f16* __restrict__ wsp, float* __restrict__ cwp,
                             float* __restrict__ cwp2) {
  int i = blockIdx.x / (NIMG + 1);
  int img = blockIdx.x % (NIMG + 1);
  if (img == NIMG) {
    int tid = threadIdx.x;
    if (tid < 16) {
      int cc = tid & 3;
      float gs = g_scale[i * 4 + cc];
      float sc = 0.2f * log1pf(expf(0.5f * gs));
      cwp[i * 24 + tid] = w_perm[i * 16 + tid] * sc;
    } else if (tid < 20) {
      int r = tid - 16;
      float acc = 0.f;
      for (int cc = 0; cc < 4; ++cc)
        acc += w_perm[i * 16 + r * 4 + cc] * g_offset[i * 4 + cc];
      cwp[i * 24 + 16 + r] = acc;
    } else if (tid < 24) {
      int j = tid - 20;
      float scale = (j < 2) ? (0.2f * LOG2E) : 0.1f;
      cwp[i * 24 + 20 + j] = b3[i * 4 + j] * scale;
    } else if (tid == 24 && i == 0) {
      float acc = 0.f;
      for (int k = 0; k < 32; ++k)
        acc += logf(0.2f * log1pf(expf(0.5f * g_scale[k])));
      cwp[192] = acc;
    }
    {
      int T2 = threadIdx.x >> 5, hi = (threadIdx.x >> 4) & 1, r = threadIdx.x & 15;
      cwp2[i * 64 + threadIdx.x] =
          b2[i * 64 + 32 * T2 + (r & 3) + 8 * (r >> 2) + 4 * hi];
    }
    return;
  }
  int lane = threadIdx.x;
  int row = lane & 31, hi = lane >> 5;
  f16 vals[8];
#pragma unroll
  for (int e = 0; e < 8; ++e) {
    int k = 8 * hi + e;
    float out = 0.f;
    if (img < 2) {
      int m = 32 * img + row;
      if (k < 4)       out = hi_part(W1[i * 256 + m * 4 + k]);
      else if (k == 4) out = hi_part(b1[i * 64 + m]);
      else out = 0.f;
    } else if (img < 10) {
      int q = img - 2, T2 = q >> 2, j = q & 3;
      int m = 32 * T2 + row;
      out = hi_part(W2[i * 4096 + m * 64 + pinv32(j, k)]);
    } else {
      int j = img - 10;
      int rr = row & 3;  // replicate W3 rows -> d3 regs 0..3 = a0..a3 everywhere
      float rs = (rr < 2) ? (0.2f * LOG2E) : 0.1f;
      out = hi_part(W3[i * 256 + rr * 64 + pinv32(j, k)] * rs);
    }
    vals[e] = (f16)out;
  }
  f16x8 vv = {vals[0], vals[1], vals[2], vals[3], vals[4], vals[5], vals[6], vals[7]};
  *(f16x8*)(wsp + ((size_t)i * NIMG + img) * 512 + (size_t)lane * 8) = vv;
}

// 8 consecutive D regs -> packed RTZ f16 + packed relu (8 VALU ops).
template <int OFF>
__device__ __forceinline__ f16x8 cvt_relu(const f32x16 d, uint32_t zero_u) {
  u32x4 u;
  u[0] = pkrtz_u(d[OFF + 0], d[OFF + 1]);
  u[1] = pkrtz_u(d[OFF + 2], d[OFF + 3]);
  u[2] = pkrtz_u(d[OFF + 4], d[OFF + 5]);
  u[3] = pkrtz_u(d[OFF + 6], d[OFF + 7]);
#pragma unroll
  for (int p = 0; p < 4; ++p) {
    uint32_t r;
    asm("v_pk_max_f16 %0, %1, %2" : "=v"(r) : "v"(u[p]), "v"(zero_u));
    u[p] = r;
  }
  return __builtin_bit_cast(f16x8, u);
}

struct Pt {
  float x0, x1, x2, x3, ld;
  uint32_t ch_pk;
};

// Dual-stream 32x32, all-f16 operands (no lo-corrections). B1 needs only
// K-slots {x0,x1,c0,c1,1} on the hi=0 half; hi=1 half is zero.
__global__ __launch_bounds__(256) void cinn_mfma_kernel(
    const float* __restrict__ q_feat, const float* __restrict__ Hc,
    const f16* __restrict__ wf, const float* __restrict__ cwp,
    const float* __restrict__ cwp2,
    float* __restrict__ out_x, float* __restrict__ out_ld, int n) {
  int lane = threadIdx.x & 63;
  int col = lane & 31;
  bool h0 = (lane < 32);
  int wave = (blockIdx.x * blockDim.x + threadIdx.x) >> 6;
  uint32_t zero_u = 0u;
  const uint32_t one_lo_pk = 0x00003C00u;  // packed f16 {1, 0}

  int pt[NS];
  Pt st[NS];
#pragma unroll
  for (int u = 0; u < NS; ++u) {
    int p = wave * (32 * NS) + u * 32 + col;
    if (p >= n) p = n - 1;  // clamped lanes compute identical results (benign)
    pt[u] = p;
    float4 xv = *reinterpret_cast<const float4*>(q_feat + (size_t)p * 4);
    st[u].x0 = xv.x; st[u].x1 = xv.y; st[u].x2 = xv.z; st[u].x3 = xv.w;
    st[u].ld = 0.f;
    float2 hv = *reinterpret_cast<const float2*>(Hc + (size_t)p * 2);
    st[u].ch_pk = pkrtz_u(hv.x, hv.y);
  }

  const f32x16 zero16 = {0.f, 0.f, 0.f, 0.f, 0.f, 0.f, 0.f, 0.f,
                         0.f, 0.f, 0.f, 0.f, 0.f, 0.f, 0.f, 0.f};

#pragma unroll 1
  for (int i = 0; i < NBLK; ++i) {
    const f16* wb = wf + (size_t)i * NIMG * 512 + (size_t)lane * 8;
    const float* cw = cwp + i * 24;

    // B1 (k=8*hi+e): hi=0 -> {x0,x1,c0,c1,1,0,0,0}; hi=1 -> 0
    f16x8 B1[NS];
#pragma unroll
    for (int u = 0; u < NS; ++u) {
      uint32_t xh_pk = pkrtz_u(st[u].x0, st[u].x1);
      u32x4 B1u = {h0 ? xh_pk : 0u,
                   h0 ? st[u].ch_pk : 0u,
                   h0 ? one_lo_pk : 0u,
                   0u};
      B1[u] = __builtin_bit_cast(f16x8, B1u);
    }

    // L1: two output tiles (features 0-31, 32-63); A-frags shared
    f16x8 bf[NS][4];
    {
      f16x8 a0 = *(const f16x8*)(wb + 0 * 512);
      f16x8 a1 = *(const f16x8*)(wb + 1 * 512);
#pragma unroll
      for (int u = 0; u < NS; ++u) {
        f32x16 d1a = MFMA32(a0, B1[u], zero16);
        f32x16 d1b = MFMA32(a1, B1[u], zero16);
        bf[u][0] = cvt_relu<0>(d1a, zero_u);
        bf[u][1] = cvt_relu<8>(d1a, zero_u);
        bf[u][2] = cvt_relu<0>(d1b, zero_u);
        bf[u][3] = cvt_relu<8>(d1b, zero_u);
      }
    }

    // L2: per output tile, K=64 via 4 chained MFMAs; streams interleaved so
    // dependent MFMAs are 2 apart; b2 (cwp2) enters as shared C-input.
    f16x8 b3f[NS][4];
#pragma unroll
    for (int T2 = 0; T2 < 2; ++T2) {
      f16x8 ap0 = *(const f16x8*)(wb + (2 + T2 * 4 + 0) * 512);
      f16x8 ap1 = *(const f16x8*)(wb + (2 + T2 * 4 + 1) * 512);
      f16x8 ap2 = *(const f16x8*)(wb + (2 + T2 * 4 + 2) * 512);
      f16x8 ap3 = *(const f16x8*)(wb + (2 + T2 * 4 + 3) * 512);
      const f32x16 cin = *(const f32x16*)(cwp2 + i * 64 + T2 * 32 + (h0 ? 0 : 16));
      f32x16 acc[NS];
#pragma unroll
      for (int u = 0; u < NS; ++u) acc[u] = MFMA32(ap0, bf[u][0], cin);
#pragma unroll
      for (int u = 0; u < NS; ++u) acc[u] = MFMA32(ap1, bf[u][1], acc[u]);
#pragma unroll
      for (int u = 0; u < NS; ++u) acc[u] = MFMA32(ap2, bf[u][2], acc[u]);
#pragma unroll
      for (int u = 0; u < NS; ++u) acc[u] = MFMA32(ap3, bf[u][3], acc[u]);
#pragma unroll
      for (int u = 0; u < NS; ++u) {
        b3f[u][2 * T2 + 0] = cvt_relu<0>(acc[u], zero_u);
        b3f[u][2 * T2 + 1] = cvt_relu<8>(acc[u], zero_u);
      }
    }

    // L3: rows replicated -> regs 0..3 = {2a0*log2e, 2a1*log2e, t2, t3}
    f32x16 d3[NS];
    {
      f16x8 a0 = *(const f16x8*)(wb + 10 * 512);
      f16x8 a1 = *(const f16x8*)(wb + 11 * 512);
      f16x8 a2 = *(const f16x8*)(wb + 12 * 512);
      f16x8 a3 = *(const f16x8*)(wb + 13 * 512);
#pragma unroll
      for (int u = 0; u < NS; ++u) d3[u] = MFMA32(a0, b3f[u][0], zero16);
#pragma unroll
      for (int u = 0; u < NS; ++u) d3[u] = MFMA32(a1, b3f[u][1], d3[u]);
#pragma unroll
      for (int u = 0; u < NS; ++u) d3[u] = MFMA32(a2, b3f[u][2], d3[u]);
#pragma unroll
      for (int u = 0; u < NS; ++u) d3[u] = MFMA32(a3, b3f[u][3], d3[u]);
    }

    // couple (shuffle-free) per stream
#pragma unroll
    for (int u = 0; u < NS; ++u) {
      float a0 = d3[u][0] + cw[20];
      float a1 = d3[u][1] + cw[21];
      float t2 = d3[u][2] + cw[22];
      float t3 = d3[u][3] + cw[23];
      float u0 = fast_exp2(a0), u1 = fast_exp2(a1);      // e^{2a}
      float s0 = fmaf(-4.f, fast_rcp(u0 + 1.f), 2.f);    // 2*tanh(a)
      float s1 = fmaf(-4.f, fast_rcp(u1 + 1.f), 2.f);
      float e0 = fast_exp2(s0 * LOG2E), e1 = fast_exp2(s1 * LOG2E);
      st[u].x2 = fmaf(st[u].x2, e0, t2);
      st[u].x3 = fmaf(st[u].x3, e1, t3);
      st[u].ld += s0 + s1;
      float nx0 = fmaf(st[u].x0, cw[0],  fmaf(st[u].x1, cw[1],  fmaf(st[u].x2, cw[2],  fmaf(st[u].x3, cw[3],  cw[16]))));
      float nx1 = fmaf(st[u].x0, cw[4],  fmaf(st[u].x1, cw[5],  fmaf(st[u].x2, cw[6],  fmaf(st[u].x3, cw[7],  cw[17]))));
      float nx2 = fmaf(st[u].x0, cw[8],  fmaf(st[u].x1, cw[9],  fmaf(st[u].x2, cw[10], fmaf(st[u].x3, cw[11], cw[18]))));
      float nx3 = fmaf(st[u].x0, cw[12], fmaf(st[u].x1, cw[13], fmaf(st[u].x2, cw[14], fmaf(st[u].x3, cw[15], cw[19]))));
      st[u].x0 = nx0; st[u].x1 = nx1; st[u].x2 = nx2; st[u].x3 = nx3;
    }
  }

  if (lane < 32) {
    float lt = cwp[192];
#pragma unroll
    for (int u = 0; u < NS; ++u) {
      *reinterpret_cast<float4*>(out_x + (size_t)pt[u] * 4) =
          make_float4(st[u].x0, st[u].x1, st[u].x2, st[u].x3);
      out_ld[pt[u]] = st[u].ld + lt;
    }
  }
}

extern "C" void kernel_launch(void* const* d_in, const int* in_sizes, int n_in,
                              void* d_out, int out_size, void* d_ws, size_t ws_size,
                              hipStream_t stream) {
  const float* q_feat   = (const float*)d_in[0];
  const float* Hc       = (const float*)d_in[1];
  const float* W1       = (const float*)d_in[2];
  const float* b1       = (const float*)d_in[3];
  const float* W2       = (const float*)d_in[4];
  const float* b2       = (const float*)d_in[5];
  const float* W3       = (const float*)d_in[6];
  const float* b3       = (const float*)d_in[7];
  const float* w_perm   = (const float*)d_in[8];
  const float* g_scale  = (const float*)d_in[9];
  const float* g_offset = (const float*)d_in[10];

  int n = in_sizes[0] / 4;
  float* out_x  = (float*)d_out;
  float* out_ld = out_x + (size_t)n * 4;
  f16* wf = (f16*)d_ws;                           // 8*14*512*2 = 114688 B
  float* cwp  = (float*)((char*)d_ws + 114688);   // 193 floats
  float* cwp2 = (float*)((char*)d_ws + 115712);   // 512 floats (b2 reordered)

  hipLaunchKernelGGL(prep_weights, dim3(NBLK * (NIMG + 1)), dim3(64), 0, stream,
                     W1, b1, W2, W3, b2, b3, w_perm, g_scale, g_offset,
                     wf, cwp, cwp2);
  int blocks = (n + 255) / 256;  // 256 points per 256-thread block (64/wave)
  hipLaunchKernelGGL(cinn_mfma_kernel, dim3(blocks), dim3(256), 0, stream,
                     q_feat, Hc, wf, cwp, cwp2, out_x, out_ld, n);
}